// Round 1
// baseline (985.700 us; speedup 1.0000x reference)
//
#include <hip/hip_runtime.h>
#include <math.h>

// ---------------------------------------------------------------------------
// Conv + affine + ReLU + fused 2x2 maxpool.
// One wave (64 threads) per (n, co-group of NCO, tile of pooled rows).
// Lane -> (ypl, xp) pooled coordinates; weights are wave-uniform (SGPR loads).
// Each lane computes the 2x2 pre-pool conv patch for NCO channels, then pools.
// ---------------------------------------------------------------------------
template <int CIN, int HIN, int NCO>
__global__ __launch_bounds__(64) void conv_pool_k(
    const float* __restrict__ in, const float* __restrict__ in2, int n2start,
    const float* __restrict__ wgt, const float* __restrict__ gg,
    const float* __restrict__ bb, float* __restrict__ out)
{
    constexpr int HP  = HIN / 2;   // pooled H/W
    constexpr int RPW = 64 / HP;   // pooled rows handled per wave

    const int lane = threadIdx.x;
    const int ypl  = lane / HP;
    const int xp   = lane % HP;
    const int n    = blockIdx.z;
    const int co0  = blockIdx.y * NCO;
    const int yp   = blockIdx.x * RPW + ypl;
    const bool active = (ypl < RPW) && (yp < HP);

    const float* src = in;
    int nn = n;
    if (in2 != nullptr && n >= n2start) { src = in2; nn = n - n2start; }
    const float* img = src + (size_t)nn * CIN * HIN * HIN;

    float acc[2][2][NCO];
#pragma unroll
    for (int a = 0; a < 2; ++a)
#pragma unroll
        for (int c = 0; c < 2; ++c)
#pragma unroll
            for (int j = 0; j < NCO; ++j) acc[a][c][j] = 0.f;

    const int y0 = 2 * yp - 1;   // top row of the 4-row input window
    const int x0 = 2 * xp - 1;   // left col of the 4-col input window

    for (int ci = 0; ci < CIN; ++ci) {
        const float* ch = img + (size_t)ci * (HIN * HIN);
        float v[4][4];
#pragma unroll
        for (int r = 0; r < 4; ++r) {
            const int yy = y0 + r;
#pragma unroll
            for (int c = 0; c < 4; ++c) {
                const int xx = x0 + c;
                const bool ok = active && (yy >= 0) && (yy < HIN) &&
                                (xx >= 0) && (xx < HIN);
                v[r][c] = ok ? ch[yy * HIN + xx] : 0.f;
            }
        }
#pragma unroll
        for (int j = 0; j < NCO; ++j) {
            const float* wp = wgt + ((size_t)(co0 + j) * CIN + ci) * 9;
#pragma unroll
            for (int u = 0; u < 3; ++u) {
#pragma unroll
                for (int t = 0; t < 3; ++t) {
                    const float wv = wp[u * 3 + t];   // wave-uniform -> SGPR
                    acc[0][0][j] = fmaf(v[u][t],         wv, acc[0][0][j]);
                    acc[0][1][j] = fmaf(v[u][t + 1],     wv, acc[0][1][j]);
                    acc[1][0][j] = fmaf(v[u + 1][t],     wv, acc[1][0][j]);
                    acc[1][1][j] = fmaf(v[u + 1][t + 1], wv, acc[1][1][j]);
                }
            }
        }
    }

    if (active) {
#pragma unroll
        for (int j = 0; j < NCO; ++j) {
            const float gv = gg[co0 + j], bv = bb[co0 + j];
            const float a00 = fmaxf(fmaf(acc[0][0][j], gv, bv), 0.f);
            const float a01 = fmaxf(fmaf(acc[0][1][j], gv, bv), 0.f);
            const float a10 = fmaxf(fmaf(acc[1][0][j], gv, bv), 0.f);
            const float a11 = fmaxf(fmaf(acc[1][1][j], gv, bv), 0.f);
            const float m = fmaxf(fmaxf(a00, a01), fmaxf(a10, a11));
            out[(((size_t)n * 64 + (co0 + j)) * HP + yp) * HP + xp] = m;
        }
    }
}

// ---------------------------------------------------------------------------
// Conv + affine + ReLU, no pool. 21x21, Cin=Cout=64.
// Wave covers 3 output rows x 21 cols (63 active lanes), NCO channels each.
// ---------------------------------------------------------------------------
template <int NCO>
__global__ __launch_bounds__(64) void conv_np_k(
    const float* __restrict__ in, const float* __restrict__ wgt,
    const float* __restrict__ gg, const float* __restrict__ bb,
    float* __restrict__ out)
{
    constexpr int H = 21;
    const int lane = threadIdx.x;
    const int yl = lane / H;            // 0..2 (lane 63 -> 3, inactive)
    const int x  = lane % H;
    const bool active = lane < 63;
    const int n   = blockIdx.z;
    const int co0 = blockIdx.y * NCO;
    const int y   = blockIdx.x * 3 + yl;

    const float* img = in + (size_t)n * 64 * H * H;

    float acc[NCO];
#pragma unroll
    for (int j = 0; j < NCO; ++j) acc[j] = 0.f;

    for (int ci = 0; ci < 64; ++ci) {
        const float* ch = img + (size_t)ci * (H * H);
        float v[3][3];
#pragma unroll
        for (int r = 0; r < 3; ++r) {
            const int yy = y - 1 + r;
#pragma unroll
            for (int c = 0; c < 3; ++c) {
                const int xx = x - 1 + c;
                const bool ok = active && (yy >= 0) && (yy < H) &&
                                (xx >= 0) && (xx < H);
                v[r][c] = ok ? ch[yy * H + xx] : 0.f;
            }
        }
#pragma unroll
        for (int j = 0; j < NCO; ++j) {
            const float* wp = wgt + ((size_t)(co0 + j) * 64 + ci) * 9;
#pragma unroll
            for (int u = 0; u < 3; ++u)
#pragma unroll
                for (int t = 0; t < 3; ++t)
                    acc[j] = fmaf(v[u][t], wp[u * 3 + t], acc[j]);
        }
    }

    if (active) {
#pragma unroll
        for (int j = 0; j < NCO; ++j) {
            const float gv = gg[co0 + j], bv = bb[co0 + j];
            const float r = fmaxf(fmaf(acc[j], gv, bv), 0.f);
            out[(((size_t)n * 64 + (co0 + j)) * H + y) * H + x] = r;
        }
    }
}

// ---------------------------------------------------------------------------
// Global average pool: (160,64,21,21) -> (160,64). One wave per (n,c).
// ---------------------------------------------------------------------------
__global__ __launch_bounds__(64) void gap_k(const float* __restrict__ in,
                                            float* __restrict__ emb)
{
    const int nc = blockIdx.x;
    const int lane = threadIdx.x;
    const float* p = in + (size_t)nc * 441;
    float s = 0.f;
    for (int i = lane; i < 441; i += 64) s += p[i];
#pragma unroll
    for (int off = 32; off > 0; off >>= 1) s += __shfl_down(s, off);
    if (lane == 0) emb[nc] = s * (1.f / 441.f);
}

// ---------------------------------------------------------------------------
// Relation head: per (b,q,w) block of 64 threads, loop over 5 shots:
// diff -> fc1(64x64)+ReLU -> fc2(32x64)+ReLU -> fc3(1x32)+sigmoid -> mean.
// ---------------------------------------------------------------------------
__global__ __launch_bounds__(64) void relation_k(
    const float* __restrict__ emb,
    const float* __restrict__ fc1w, const float* __restrict__ fc1b,
    const float* __restrict__ fc2w, const float* __restrict__ fc2b,
    const float* __restrict__ fc3w, const float* __restrict__ fc3b,
    float* __restrict__ out)
{
    const int idx = blockIdx.x;          // (b*15+q)*5 + w
    const int w  = idx % 5;
    const int bq = idx / 5;
    const int b  = bq / 15;
    const int t  = threadIdx.x;

    __shared__ float dif[64], h1v[64], h2v[32];
    const float qv = emb[(size_t)bq * 64 + t];

    float ssum = 0.f;
    for (int s = 0; s < 5; ++s) {
        const int simg = 60 + ((b * 5 + w) * 5 + s);
        __syncthreads();
        dif[t] = fabsf(qv - emb[(size_t)simg * 64 + t]);
        __syncthreads();
        float a = fc1b[t];
        for (int d = 0; d < 64; ++d) a = fmaf(fc1w[t * 64 + d], dif[d], a);
        a = fmaxf(a, 0.f);
        __syncthreads();
        h1v[t] = a;
        __syncthreads();
        if (t < 32) {
            float h = fc2b[t];
            for (int d = 0; d < 64; ++d) h = fmaf(fc2w[t * 64 + d], h1v[d], h);
            h2v[t] = fmaxf(h, 0.f);
        }
        __syncthreads();
        float p = (t < 32) ? fc3w[t] * h2v[t] : 0.f;
#pragma unroll
        for (int off = 32; off > 0; off >>= 1) p += __shfl_down(p, off);
        if (t == 0) {
            const float z = p + fc3b[0];
            ssum += 1.f / (1.f + expf(-z));
        }
    }
    if (t == 0) out[idx] = ssum * 0.2f;   // mean over 5 shots
}

// ---------------------------------------------------------------------------
extern "C" void kernel_launch(void* const* d_in, const int* in_sizes, int n_in,
                              void* d_out, int out_size, void* d_ws, size_t ws_size,
                              hipStream_t stream)
{
    const float* q    = (const float*)d_in[0];
    const float* s    = (const float*)d_in[1];
    const float* w1   = (const float*)d_in[2];
    const float* g1   = (const float*)d_in[3];
    const float* b1p  = (const float*)d_in[4];
    const float* w2   = (const float*)d_in[5];
    const float* g2   = (const float*)d_in[6];
    const float* b2p  = (const float*)d_in[7];
    const float* w3   = (const float*)d_in[8];
    const float* g3   = (const float*)d_in[9];
    const float* b3p  = (const float*)d_in[10];
    const float* w4   = (const float*)d_in[11];
    const float* g4   = (const float*)d_in[12];
    const float* b4p  = (const float*)d_in[13];
    const float* fc1w = (const float*)d_in[14];
    const float* fc1b = (const float*)d_in[15];
    const float* fc2w = (const float*)d_in[16];
    const float* fc2b = (const float*)d_in[17];
    const float* fc3w = (const float*)d_in[18];
    const float* fc3b = (const float*)d_in[19];
    float* out = (float*)d_out;

    char* ws = (char*)d_ws;
    const size_t S1 = (size_t)160 * 64 * 42 * 42;   // elements of conv1-out
    const size_t S2 = (size_t)160 * 64 * 21 * 21;   // elements of conv2/3/4-out
    float* bf1  = (float*)ws;                    // [0, 72.25MB)
    float* bf2  = (float*)(ws + S1 * 4);         // [72.25, 90.3MB)
    float* bf3  = (float*)ws;                    // reuse bf1 region [0, 18MB)
    float* bf4  = (float*)(ws + S2 * 4);         // [18, 36.1MB) inside bf1 region
    float* embv = (float*)(ws + (S1 + S2) * 4);  // 160*64 floats

    // conv1: (160,3,84,84) -> pooled (160,64,42,42)
    conv_pool_k<3, 84, 4><<<dim3(42, 16, 160), 64, 0, stream>>>(
        q, s, 60, w1, g1, b1p, bf1);
    // conv2: (160,64,42,42) -> pooled (160,64,21,21)
    conv_pool_k<64, 42, 4><<<dim3(7, 16, 160), 64, 0, stream>>>(
        bf1, nullptr, 1 << 30, w2, g2, b2p, bf2);
    // conv3: (160,64,21,21) -> (160,64,21,21)
    conv_np_k<4><<<dim3(7, 16, 160), 64, 0, stream>>>(bf2, w3, g3, b3p, bf3);
    // conv4
    conv_np_k<4><<<dim3(7, 16, 160), 64, 0, stream>>>(bf3, w4, g4, b4p, bf4);
    // global average pool -> embeddings (160,64)
    gap_k<<<dim3(160 * 64), 64, 0, stream>>>(bf4, embv);
    // relation head -> (60,5)
    relation_k<<<dim3(300), 64, 0, stream>>>(
        embv, fc1w, fc1b, fc2w, fc2b, fc3w, fc3b, out);
}

// Round 2
// 598.859 us; speedup vs baseline: 1.6460x; 1.6460x over previous
//
#include <hip/hip_runtime.h>
#include <math.h>

// ---------------------------------------------------------------------------
// Conv + affine + ReLU + fused 2x2 maxpool.
// One wave per (n, co-group of NCO, strip of 64 pooled pixels).
// Lane -> linear pooled pixel (yp,xp); weights are wave-uniform (SGPR loads).
// Each lane computes the 2x2 pre-pool conv patch for NCO channels, then pools.
// Per ci: 16 vector loads, 36*NCO FMAs.
// ---------------------------------------------------------------------------
template <int CIN, int HIN, int NCO>
__global__ __launch_bounds__(64) void conv_pool_k(
    const float* __restrict__ in, const float* __restrict__ in2, int n2start,
    const float* __restrict__ wgt, const float* __restrict__ gg,
    const float* __restrict__ bb, float* __restrict__ out)
{
    constexpr int HP = HIN / 2;    // pooled H/W

    const int idx  = blockIdx.x * 64 + threadIdx.x;  // linear pooled pixel
    const int yp   = idx / HP;
    const int xp   = idx % HP;
    const int n    = blockIdx.z;
    const int co0  = blockIdx.y * NCO;
    const bool active = yp < HP;

    const float* src = in;
    int nn = n;
    if (in2 != nullptr && n >= n2start) { src = in2; nn = n - n2start; }
    const float* img = src + (size_t)nn * CIN * HIN * HIN;

    float acc[2][2][NCO];
#pragma unroll
    for (int a = 0; a < 2; ++a)
#pragma unroll
        for (int c = 0; c < 2; ++c)
#pragma unroll
            for (int j = 0; j < NCO; ++j) acc[a][c][j] = 0.f;

    const int y0 = 2 * yp - 1;   // top row of the 4-row input window
    const int x0 = 2 * xp - 1;   // left col of the 4-col input window

    for (int ci = 0; ci < CIN; ++ci) {
        const float* ch = img + (size_t)ci * (HIN * HIN);
        float v[4][4];
#pragma unroll
        for (int r = 0; r < 4; ++r) {
            const int yy = y0 + r;
#pragma unroll
            for (int c = 0; c < 4; ++c) {
                const int xx = x0 + c;
                const bool ok = active && (yy >= 0) && (yy < HIN) &&
                                (xx >= 0) && (xx < HIN);
                v[r][c] = ok ? ch[yy * HIN + xx] : 0.f;
            }
        }
#pragma unroll
        for (int j = 0; j < NCO; ++j) {
            const float* wp = wgt + ((size_t)(co0 + j) * CIN + ci) * 9;
#pragma unroll
            for (int u = 0; u < 3; ++u) {
#pragma unroll
                for (int t = 0; t < 3; ++t) {
                    const float wv = wp[u * 3 + t];   // wave-uniform -> SGPR
                    acc[0][0][j] = fmaf(v[u][t],         wv, acc[0][0][j]);
                    acc[0][1][j] = fmaf(v[u][t + 1],     wv, acc[0][1][j]);
                    acc[1][0][j] = fmaf(v[u + 1][t],     wv, acc[1][0][j]);
                    acc[1][1][j] = fmaf(v[u + 1][t + 1], wv, acc[1][1][j]);
                }
            }
        }
    }

    if (active) {
#pragma unroll
        for (int j = 0; j < NCO; ++j) {
            const float gv = gg[co0 + j], bv = bb[co0 + j];
            const float a00 = fmaxf(fmaf(acc[0][0][j], gv, bv), 0.f);
            const float a01 = fmaxf(fmaf(acc[0][1][j], gv, bv), 0.f);
            const float a10 = fmaxf(fmaf(acc[1][0][j], gv, bv), 0.f);
            const float a11 = fmaxf(fmaf(acc[1][1][j], gv, bv), 0.f);
            const float m = fmaxf(fmaxf(a00, a01), fmaxf(a10, a11));
            out[(((size_t)n * 64 + (co0 + j)) * HP + yp) * HP + xp] = m;
        }
    }
}

// ---------------------------------------------------------------------------
// Conv + affine + ReLU, no pool. 21x21, Cin=Cout=64.
// One wave per (n, co-group of NCO, strip of 64 pixels). Per ci: 9 loads,
// 9*NCO FMAs.
// ---------------------------------------------------------------------------
template <int NCO>
__global__ __launch_bounds__(64) void conv_np_k(
    const float* __restrict__ in, const float* __restrict__ wgt,
    const float* __restrict__ gg, const float* __restrict__ bb,
    float* __restrict__ out)
{
    constexpr int H = 21;
    const int idx = blockIdx.x * 64 + threadIdx.x;   // linear pixel in 441
    const int y = idx / H;
    const int x = idx % H;
    const bool active = y < H;
    const int n   = blockIdx.z;
    const int co0 = blockIdx.y * NCO;

    const float* img = in + (size_t)n * 64 * H * H;

    float acc[NCO];
#pragma unroll
    for (int j = 0; j < NCO; ++j) acc[j] = 0.f;

    for (int ci = 0; ci < 64; ++ci) {
        const float* ch = img + (size_t)ci * (H * H);
        float v[3][3];
#pragma unroll
        for (int r = 0; r < 3; ++r) {
            const int yy = y - 1 + r;
#pragma unroll
            for (int c = 0; c < 3; ++c) {
                const int xx = x - 1 + c;
                const bool ok = active && (yy >= 0) && (yy < H) &&
                                (xx >= 0) && (xx < H);
                v[r][c] = ok ? ch[yy * H + xx] : 0.f;
            }
        }
#pragma unroll
        for (int j = 0; j < NCO; ++j) {
            const float* wp = wgt + ((size_t)(co0 + j) * 64 + ci) * 9;
#pragma unroll
            for (int u = 0; u < 3; ++u)
#pragma unroll
                for (int t = 0; t < 3; ++t)
                    acc[j] = fmaf(v[u][t], wp[u * 3 + t], acc[j]);
        }
    }

    if (active) {
#pragma unroll
        for (int j = 0; j < NCO; ++j) {
            const float gv = gg[co0 + j], bv = bb[co0 + j];
            const float r = fmaxf(fmaf(acc[j], gv, bv), 0.f);
            out[(((size_t)n * 64 + (co0 + j)) * H + y) * H + x] = r;
        }
    }
}

// ---------------------------------------------------------------------------
// Global average pool: (160,64,21,21) -> (160,64). One wave per (n,c).
// ---------------------------------------------------------------------------
__global__ __launch_bounds__(64) void gap_k(const float* __restrict__ in,
                                            float* __restrict__ emb)
{
    const int nc = blockIdx.x;
    const int lane = threadIdx.x;
    const float* p = in + (size_t)nc * 441;
    float s = 0.f;
    for (int i = lane; i < 441; i += 64) s += p[i];
#pragma unroll
    for (int off = 32; off > 0; off >>= 1) s += __shfl_down(s, off);
    if (lane == 0) emb[nc] = s * (1.f / 441.f);
}

// ---------------------------------------------------------------------------
// Relation head: per (b,q,w) block of 64 threads, loop over 5 shots:
// diff -> fc1(64x64)+ReLU -> fc2(32x64)+ReLU -> fc3(1x32)+sigmoid -> mean.
// ---------------------------------------------------------------------------
__global__ __launch_bounds__(64) void relation_k(
    const float* __restrict__ emb,
    const float* __restrict__ fc1w, const float* __restrict__ fc1b,
    const float* __restrict__ fc2w, const float* __restrict__ fc2b,
    const float* __restrict__ fc3w, const float* __restrict__ fc3b,
    float* __restrict__ out)
{
    const int idx = blockIdx.x;          // (b*15+q)*5 + w
    const int w  = idx % 5;
    const int bq = idx / 5;
    const int b  = bq / 15;
    const int t  = threadIdx.x;

    __shared__ float dif[64], h1v[64], h2v[32];
    const float qv = emb[(size_t)bq * 64 + t];

    float ssum = 0.f;
    for (int s = 0; s < 5; ++s) {
        const int simg = 60 + ((b * 5 + w) * 5 + s);
        __syncthreads();
        dif[t] = fabsf(qv - emb[(size_t)simg * 64 + t]);
        __syncthreads();
        float a = fc1b[t];
        for (int d = 0; d < 64; ++d) a = fmaf(fc1w[t * 64 + d], dif[d], a);
        a = fmaxf(a, 0.f);
        __syncthreads();
        h1v[t] = a;
        __syncthreads();
        if (t < 32) {
            float h = fc2b[t];
            for (int d = 0; d < 64; ++d) h = fmaf(fc2w[t * 64 + d], h1v[d], h);
            h2v[t] = fmaxf(h, 0.f);
        }
        __syncthreads();
        float p = (t < 32) ? fc3w[t] * h2v[t] : 0.f;
#pragma unroll
        for (int off = 32; off > 0; off >>= 1) p += __shfl_down(p, off);
        if (t == 0) {
            const float z = p + fc3b[0];
            ssum += 1.f / (1.f + expf(-z));
        }
    }
    if (t == 0) out[idx] = ssum * 0.2f;   // mean over 5 shots
}

// ---------------------------------------------------------------------------
extern "C" void kernel_launch(void* const* d_in, const int* in_sizes, int n_in,
                              void* d_out, int out_size, void* d_ws, size_t ws_size,
                              hipStream_t stream)
{
    const float* q    = (const float*)d_in[0];
    const float* s    = (const float*)d_in[1];
    const float* w1   = (const float*)d_in[2];
    const float* g1   = (const float*)d_in[3];
    const float* b1p  = (const float*)d_in[4];
    const float* w2   = (const float*)d_in[5];
    const float* g2   = (const float*)d_in[6];
    const float* b2p  = (const float*)d_in[7];
    const float* w3   = (const float*)d_in[8];
    const float* g3   = (const float*)d_in[9];
    const float* b3p  = (const float*)d_in[10];
    const float* w4   = (const float*)d_in[11];
    const float* g4   = (const float*)d_in[12];
    const float* b4p  = (const float*)d_in[13];
    const float* fc1w = (const float*)d_in[14];
    const float* fc1b = (const float*)d_in[15];
    const float* fc2w = (const float*)d_in[16];
    const float* fc2b = (const float*)d_in[17];
    const float* fc3w = (const float*)d_in[18];
    const float* fc3b = (const float*)d_in[19];
    float* out = (float*)d_out;

    char* ws = (char*)d_ws;
    const size_t S1 = (size_t)160 * 64 * 42 * 42;   // elements of conv1-out
    const size_t S2 = (size_t)160 * 64 * 21 * 21;   // elements of conv2/3/4-out
    float* bf1  = (float*)ws;                    // [0, 72.25MB)
    float* bf2  = (float*)(ws + S1 * 4);         // [72.25, 90.3MB)
    float* bf3  = (float*)ws;                    // reuse bf1 region [0, 18MB)
    float* bf4  = (float*)(ws + S2 * 4);         // [18, 36.1MB) inside bf1 region
    float* embv = (float*)(ws + (S1 + S2) * 4);  // 160*64 floats

    // conv1: (160,3,84,84) -> pooled (160,64,42,42). 42*42=1764 px -> 28 strips
    conv_pool_k<3, 84, 16><<<dim3(28, 4, 160), 64, 0, stream>>>(
        q, s, 60, w1, g1, b1p, bf1);
    // conv2: (160,64,42,42) -> pooled (160,64,21,21). 441 px -> 7 strips
    conv_pool_k<64, 42, 16><<<dim3(7, 4, 160), 64, 0, stream>>>(
        bf1, nullptr, 1 << 30, w2, g2, b2p, bf2);
    // conv3: (160,64,21,21) -> (160,64,21,21)
    conv_np_k<16><<<dim3(7, 4, 160), 64, 0, stream>>>(bf2, w3, g3, b3p, bf3);
    // conv4
    conv_np_k<16><<<dim3(7, 4, 160), 64, 0, stream>>>(bf3, w4, g4, b4p, bf4);
    // global average pool -> embeddings (160,64)
    gap_k<<<dim3(160 * 64), 64, 0, stream>>>(bf4, embv);
    // relation head -> (60,5)
    relation_k<<<dim3(300), 64, 0, stream>>>(
        embv, fc1w, fc1b, fc2w, fc2b, fc3w, fc3b, out);
}

// Round 3
// 284.555 us; speedup vs baseline: 3.4640x; 2.1045x over previous
//
#include <hip/hip_runtime.h>
#include <math.h>

typedef unsigned short ushort_t;
typedef __attribute__((ext_vector_type(8))) short bf16x8;
typedef __attribute__((ext_vector_type(16))) float f32x16;

__device__ __forceinline__ ushort_t f2bf(float f) {
    unsigned u = __float_as_uint(f);
    u += 0x7fffu + ((u >> 16) & 1u);          // RNE
    return (ushort_t)(u >> 16);
}
__device__ __forceinline__ float bf2f(ushort_t h) {
    return __uint_as_float(((unsigned)h) << 16);
}

// ---------------------------------------------------------------------------
// Zero the 1-px halo of a padded channels-last bf16 buffer [160][HP][HP][64].
// ---------------------------------------------------------------------------
template <int HP>
__global__ __launch_bounds__(256) void border_zero_k(ushort_t* __restrict__ buf)
{
    const int n = blockIdx.x, t = threadIdx.x;
    constexpr int W = HP - 2;
    constexpr int NB = 2 * HP + 2 * W;
    for (int i = t; i < NB; i += blockDim.x) {
        int yy, xx;
        if (i < HP)            { yy = 0;            xx = i; }
        else if (i < 2 * HP)   { yy = HP - 1;       xx = i - HP; }
        else if (i < 2*HP + W) { yy = i - 2*HP + 1; xx = 0; }
        else                   { yy = i - 2*HP - W + 1; xx = HP - 1; }
        uint4* p = (uint4*)(buf + ((size_t)n * HP * HP + yy * HP + xx) * 64);
        const uint4 z = make_uint4(0u, 0u, 0u, 0u);
#pragma unroll
        for (int k = 0; k < 8; ++k) p[k] = z;
    }
}

// ---------------------------------------------------------------------------
// conv1: f32 direct, CIN=3, fused affine+ReLU+2x2 pool.
// 4-wave blocks; writes bf16 channels-last padded [160][44][44][64] interior.
// ---------------------------------------------------------------------------
__global__ __launch_bounds__(256) void conv1_k(
    const float* __restrict__ qin, const float* __restrict__ sin, int n2start,
    const float* __restrict__ wgt, const float* __restrict__ gg,
    const float* __restrict__ bb, ushort_t* __restrict__ outp)
{
    constexpr int HIN = 84, HP = 42, CIN = 3;
    const int idx = blockIdx.x * 256 + threadIdx.x;
    const int yp = idx / HP, xp = idx % HP;
    const int n = blockIdx.z;
    const int co0 = blockIdx.y * 16;
    const bool active = idx < HP * HP;

    const float* src = qin; int nn = n;
    if (n >= n2start) { src = sin; nn = n - n2start; }
    const float* img = src + (size_t)nn * CIN * HIN * HIN;

    float acc[2][2][16];
#pragma unroll
    for (int a = 0; a < 2; ++a)
#pragma unroll
        for (int c = 0; c < 2; ++c)
#pragma unroll
            for (int j = 0; j < 16; ++j) acc[a][c][j] = 0.f;

    const int y0 = 2 * yp - 1, x0 = 2 * xp - 1;

    for (int ci = 0; ci < CIN; ++ci) {
        const float* ch = img + (size_t)ci * (HIN * HIN);
        float v[4][4];
#pragma unroll
        for (int r = 0; r < 4; ++r) {
            const int yy = y0 + r;
#pragma unroll
            for (int c = 0; c < 4; ++c) {
                const int xx = x0 + c;
                const bool ok = active && (yy >= 0) && (yy < HIN) &&
                                (xx >= 0) && (xx < HIN);
                v[r][c] = ok ? ch[yy * HIN + xx] : 0.f;
            }
        }
#pragma unroll
        for (int j = 0; j < 16; ++j) {
            const float* wp = wgt + ((size_t)(co0 + j) * CIN + ci) * 9;
#pragma unroll
            for (int u = 0; u < 3; ++u)
#pragma unroll
                for (int t = 0; t < 3; ++t) {
                    const float wv = wp[u * 3 + t];
                    acc[0][0][j] = fmaf(v[u][t],         wv, acc[0][0][j]);
                    acc[0][1][j] = fmaf(v[u][t + 1],     wv, acc[0][1][j]);
                    acc[1][0][j] = fmaf(v[u + 1][t],     wv, acc[1][0][j]);
                    acc[1][1][j] = fmaf(v[u + 1][t + 1], wv, acc[1][1][j]);
                }
        }
    }

    if (active) {
        unsigned pk[8];
#pragma unroll
        for (int jj = 0; jj < 8; ++jj) {
            ushort_t half2[2];
#pragma unroll
            for (int e = 0; e < 2; ++e) {
                const int j = 2 * jj + e;
                const float gv = gg[co0 + j], bv = bb[co0 + j];
                const float a00 = fmaxf(fmaf(acc[0][0][j], gv, bv), 0.f);
                const float a01 = fmaxf(fmaf(acc[0][1][j], gv, bv), 0.f);
                const float a10 = fmaxf(fmaf(acc[1][0][j], gv, bv), 0.f);
                const float a11 = fmaxf(fmaf(acc[1][1][j], gv, bv), 0.f);
                half2[e] = f2bf(fmaxf(fmaxf(a00, a01), fmaxf(a10, a11)));
            }
            pk[jj] = (unsigned)half2[0] | ((unsigned)half2[1] << 16);
        }
        ushort_t* dst = outp + ((size_t)n * 1936 + (yp + 1) * 44 + (xp + 1)) * 64 + co0;
        uint4* d4 = (uint4*)dst;
        d4[0] = make_uint4(pk[0], pk[1], pk[2], pk[3]);
        d4[1] = make_uint4(pk[4], pk[5], pk[6], pk[7]);
    }
}

// ---------------------------------------------------------------------------
// MFMA implicit-GEMM conv 3x3, Cin=Cout=64, bf16 in / f32 accum.
// M = output pixels (POOL: pooled_px*4+quadrant), N = 64 co, K = 9 taps * 64 ci.
// Block: 4 waves, each 2 M-tiles(32) x 2 N-tiles(32), v_mfma_f32_32x32x16_bf16.
// Weights staged to LDS [9][64][32] bf16 per ci-half, XOR-swizzled (G4 recipe).
// EPI: 0 = affine+ReLU+2x2pool -> padded [23][23] write, 1 = padded write,
//      2 = compact [m][64] write (feeds GAP).
// ---------------------------------------------------------------------------
template <int HINP, int POOL, int EPI>
__global__ __launch_bounds__(256, 4) void conv_mfma_k(
    const ushort_t* __restrict__ in, const float* __restrict__ wgt,
    const float* __restrict__ gg, const float* __restrict__ bb,
    ushort_t* __restrict__ outp)
{
    constexpr int MIMG = POOL ? 1764 : 441;
    constexpr int MTOT = 160 * MIMG;
    constexpr int CH2 = HINP * HINP * 64;

    __shared__ __align__(16) ushort_t wlds[9 * 64 * 32];

    const int tid = threadIdx.x;
    const int wv = tid >> 6, lane = tid & 63;
    const int l31 = lane & 31, h = lane >> 5;
    const int wave_m = blockIdx.x * 256 + wv * 64;

    // per-lane A-row base byte offsets (2 M-tiles)
    long aoff[2];
#pragma unroll
    for (int t = 0; t < 2; ++t) {
        int m = wave_m + t * 32 + l31;
        if (m >= MTOT) m = 0;
        int n, y, x;
        if (POOL) {
            n = m / MIMG; const int r = m % MIMG;
            const int p = r >> 2, qd = r & 3;
            const int py = p / 21, px = p % 21;
            y = 2 * py + (qd >> 1); x = 2 * px + (qd & 1);
        } else {
            n = m / MIMG; const int r = m % MIMG;
            y = r / 21; x = r % 21;
        }
        aoff[t] = ((long)n * CH2 + (y * HINP + x) * 64) * 2 + h * 16;
    }

    // B LDS offsets (ushort units), tap-independent part, per (nt, kl)
    int boff[2][2];
#pragma unroll
    for (int nt = 0; nt < 2; ++nt) {
        const int co = nt * 32 + l31;
#pragma unroll
        for (int kl = 0; kl < 2; ++kl)
            boff[nt][kl] = co * 32 + (((kl * 2 + h) ^ (co & 3)) << 3);
    }

    f32x16 acc[2][2];
#pragma unroll
    for (int t = 0; t < 2; ++t)
#pragma unroll
        for (int nt = 0; nt < 2; ++nt)
#pragma unroll
            for (int r = 0; r < 16; ++r) acc[t][nt][r] = 0.f;

    const char* inb = (const char*)in;

    for (int pass = 0; pass < 2; ++pass) {
        if (pass) __syncthreads();
        // stage weight half: wlds[tap][co][ci'] = bf16(wgt[co][pass*32+ci][tap])
        for (int idx = tid; idx < 9 * 64 * 32; idx += 256) {
            const int tap = idx >> 11;
            const int rem = idx & 2047;
            const int co = rem >> 5, cil = rem & 31;
            const float v = wgt[co * 576 + (pass * 32 + cil) * 9 + tap];
            const int chunk = (cil >> 3) ^ (co & 3);
            wlds[tap * 2048 + co * 32 + chunk * 8 + (cil & 7)] = f2bf(v);
        }
        __syncthreads();

#pragma unroll
        for (int tap = 0; tap < 9; ++tap) {
            const int tapoff = ((tap / 3) * HINP + (tap % 3)) * 128;
#pragma unroll
            for (int kl = 0; kl < 2; ++kl) {
                const int kk = pass * 2 + kl;
                const bf16x8 a0 = *(const bf16x8*)(inb + aoff[0] + tapoff + kk * 32);
                const bf16x8 a1 = *(const bf16x8*)(inb + aoff[1] + tapoff + kk * 32);
#pragma unroll
                for (int nt = 0; nt < 2; ++nt) {
                    const bf16x8 b = *(const bf16x8*)&wlds[tap * 2048 + boff[nt][kl]];
                    acc[0][nt] = __builtin_amdgcn_mfma_f32_32x32x16_bf16(
                        a0, b, acc[0][nt], 0, 0, 0);
                    acc[1][nt] = __builtin_amdgcn_mfma_f32_32x32x16_bf16(
                        a1, b, acc[1][nt], 0, 0, 0);
                }
            }
        }
    }

    // epilogue
    float gv2[2], bv2[2];
#pragma unroll
    for (int nt = 0; nt < 2; ++nt) {
        gv2[nt] = gg[nt * 32 + l31];
        bv2[nt] = bb[nt * 32 + l31];
    }

    if (EPI == 0) {
        // affine+ReLU+2x2 maxpool, write padded [n][23][23][64]
#pragma unroll
        for (int t = 0; t < 2; ++t) {
#pragma unroll
            for (int g = 0; g < 4; ++g) {
                const int mbase = wave_m + t * 32 + 8 * g + 4 * h;
                if (mbase >= MTOT) continue;
                const int P = mbase >> 2;
                const int n = P / 441; const int rp = P % 441;
                const int py = rp / 21, px = rp % 21;
                ushort_t* drow =
                    outp + ((size_t)n * 529 + (py + 1) * 23 + (px + 1)) * 64;
#pragma unroll
                for (int nt = 0; nt < 2; ++nt) {
                    float mx = 0.f;   // ReLU lower bound
#pragma unroll
                    for (int q = 0; q < 4; ++q)
                        mx = fmaxf(mx, fmaf(acc[t][nt][4 * g + q], gv2[nt], bv2[nt]));
                    drow[nt * 32 + l31] = f2bf(mx);
                }
            }
        }
    } else {
#pragma unroll
        for (int t = 0; t < 2; ++t) {
#pragma unroll
            for (int r = 0; r < 16; ++r) {
                const int m = wave_m + t * 32 + (r & 3) + 8 * (r >> 2) + 4 * h;
                if (m >= MTOT) continue;
                size_t obase;
                if (EPI == 1) {
                    const int n = m / 441; const int rr = m % 441;
                    const int y = rr / 21, x = rr % 21;
                    obase = ((size_t)n * 529 + (y + 1) * 23 + (x + 1)) * 64;
                } else {
                    obase = (size_t)m * 64;
                }
#pragma unroll
                for (int nt = 0; nt < 2; ++nt) {
                    const float v =
                        fmaxf(fmaf(acc[t][nt][r], gv2[nt], bv2[nt]), 0.f);
                    outp[obase + nt * 32 + l31] = f2bf(v);
                }
            }
        }
    }
}

// ---------------------------------------------------------------------------
// Global average pool over compact channels-last conv4 output -> emb f32.
// ---------------------------------------------------------------------------
__global__ __launch_bounds__(256) void gap2_k(const ushort_t* __restrict__ o4,
                                              float* __restrict__ emb)
{
    const int n = blockIdx.x, t = threadIdx.x;
    const int co = t & 63, part = t >> 6;
    float s = 0.f;
    for (int pix = part; pix < 441; pix += 4)
        s += bf2f(o4[((size_t)n * 441 + pix) * 64 + co]);
    __shared__ float red[4][64];
    red[part][co] = s;
    __syncthreads();
    if (part == 0)
        emb[(size_t)n * 64 + co] =
            (red[0][co] + red[1][co] + red[2][co] + red[3][co]) * (1.f / 441.f);
}

// ---------------------------------------------------------------------------
// Relation head (unchanged).
// ---------------------------------------------------------------------------
__global__ __launch_bounds__(64) void relation_k(
    const float* __restrict__ emb,
    const float* __restrict__ fc1w, const float* __restrict__ fc1b,
    const float* __restrict__ fc2w, const float* __restrict__ fc2b,
    const float* __restrict__ fc3w, const float* __restrict__ fc3b,
    float* __restrict__ out)
{
    const int idx = blockIdx.x;
    const int w = idx % 5;
    const int bq = idx / 5;
    const int b = bq / 15;
    const int t = threadIdx.x;

    __shared__ float dif[64], h1v[64], h2v[32];
    const float qv = emb[(size_t)bq * 64 + t];

    float ssum = 0.f;
    for (int s = 0; s < 5; ++s) {
        const int simg = 60 + ((b * 5 + w) * 5 + s);
        __syncthreads();
        dif[t] = fabsf(qv - emb[(size_t)simg * 64 + t]);
        __syncthreads();
        float a = fc1b[t];
        for (int d = 0; d < 64; ++d) a = fmaf(fc1w[t * 64 + d], dif[d], a);
        a = fmaxf(a, 0.f);
        __syncthreads();
        h1v[t] = a;
        __syncthreads();
        if (t < 32) {
            float h = fc2b[t];
            for (int d = 0; d < 64; ++d) h = fmaf(fc2w[t * 64 + d], h1v[d], h);
            h2v[t] = fmaxf(h, 0.f);
        }
        __syncthreads();
        float p = (t < 32) ? fc3w[t] * h2v[t] : 0.f;
#pragma unroll
        for (int off = 32; off > 0; off >>= 1) p += __shfl_down(p, off);
        if (t == 0) {
            const float z = p + fc3b[0];
            ssum += 1.f / (1.f + expf(-z));
        }
    }
    if (t == 0) out[idx] = ssum * 0.2f;
}

// ---------------------------------------------------------------------------
extern "C" void kernel_launch(void* const* d_in, const int* in_sizes, int n_in,
                              void* d_out, int out_size, void* d_ws, size_t ws_size,
                              hipStream_t stream)
{
    const float* q    = (const float*)d_in[0];
    const float* s    = (const float*)d_in[1];
    const float* w1   = (const float*)d_in[2];
    const float* g1   = (const float*)d_in[3];
    const float* b1p  = (const float*)d_in[4];
    const float* w2   = (const float*)d_in[5];
    const float* g2   = (const float*)d_in[6];
    const float* b2p  = (const float*)d_in[7];
    const float* w3   = (const float*)d_in[8];
    const float* g3   = (const float*)d_in[9];
    const float* b3p  = (const float*)d_in[10];
    const float* w4   = (const float*)d_in[11];
    const float* g4   = (const float*)d_in[12];
    const float* b4p  = (const float*)d_in[13];
    const float* fc1w = (const float*)d_in[14];
    const float* fc1b = (const float*)d_in[15];
    const float* fc2w = (const float*)d_in[16];
    const float* fc2b = (const float*)d_in[17];
    const float* fc3w = (const float*)d_in[18];
    const float* fc3b = (const float*)d_in[19];
    float* out = (float*)d_out;

    char* ws = (char*)d_ws;
    ushort_t* P1  = (ushort_t*)ws;                    // 160*44*44*64 bf16 = 39,649,280 B
    ushort_t* P2  = (ushort_t*)(ws + 39649280);       // 160*23*23*64 bf16 = 10,833,920 B
    ushort_t* P3  = (ushort_t*)(ws + 50483200);       // same
    ushort_t* O4  = (ushort_t*)(ws + 61317120);       // 160*441*64 bf16 = 9,031,680 B
    float*    embv = (float*)(ws + 70348800);         // 160*64 f32

    border_zero_k<44><<<dim3(160), 192, 0, stream>>>(P1);
    border_zero_k<23><<<dim3(160), 96, 0, stream>>>(P2);
    border_zero_k<23><<<dim3(160), 96, 0, stream>>>(P3);

    // conv1: f32 direct -> P1 interior (bf16 channels-last padded)
    conv1_k<<<dim3(7, 4, 160), 256, 0, stream>>>(q, s, 60, w1, g1, b1p, P1);
    // conv2: MFMA, pool -> P2.  M = 160*1764 -> 1103 blocks of 256
    conv_mfma_k<44, 1, 0><<<dim3(1103), 256, 0, stream>>>(P1, w2, g2, b2p, P2);
    // conv3: MFMA -> P3.  M = 160*441 -> 276 blocks
    conv_mfma_k<23, 0, 1><<<dim3(276), 256, 0, stream>>>(P2, w3, g3, b3p, P3);
    // conv4: MFMA -> compact O4
    conv_mfma_k<23, 0, 2><<<dim3(276), 256, 0, stream>>>(P3, w4, g4, b4p, O4);

    gap2_k<<<dim3(160), 256, 0, stream>>>(O4, embv);
    relation_k<<<dim3(300), 64, 0, stream>>>(
        embv, fc1w, fc1b, fc2w, fc2b, fc3w, fc3b, out);
}

// Round 4
// 199.951 us; speedup vs baseline: 4.9297x; 1.4231x over previous
//
#include <hip/hip_runtime.h>
#include <math.h>

typedef unsigned short ushort_t;
typedef __attribute__((ext_vector_type(8))) short bf16x8;
typedef __attribute__((ext_vector_type(16))) float f32x16;

__device__ __forceinline__ ushort_t f2bf(float f) {
    unsigned u = __float_as_uint(f);
    u += 0x7fffu + ((u >> 16) & 1u);          // RNE
    return (ushort_t)(u >> 16);
}
__device__ __forceinline__ float bf2f(ushort_t h) {
    return __uint_as_float(((unsigned)h) << 16);
}

// ---------------------------------------------------------------------------
// Pack NCHW f32 input (3ch) -> padded channels-last bf16 [160][86][86][8]
// (ci 0..2 real, 3..7 zero; halo pixels all-zero).
// ---------------------------------------------------------------------------
__global__ __launch_bounds__(256) void pack_k(const float* __restrict__ q,
                                              const float* __restrict__ s,
                                              ushort_t* __restrict__ p0)
{
    const int n = blockIdx.x;
    const float* src; int nn;
    if (n < 60) { src = q; nn = n; } else { src = s; nn = n - 60; }
    const float* img = src + (size_t)nn * 3 * 7056;
    for (int px = threadIdx.x; px < 7396; px += 256) {
        const int y = px / 86, x = px % 86;
        uint4 v = make_uint4(0u, 0u, 0u, 0u);
        if (y >= 1 && y <= 84 && x >= 1 && x <= 84) {
            const int o = (y - 1) * 84 + (x - 1);
            const unsigned c0 = f2bf(img[o]);
            const unsigned c1 = f2bf(img[7056 + o]);
            const unsigned c2 = f2bf(img[14112 + o]);
            v.x = c0 | (c1 << 16);
            v.y = c2;
        }
        *(uint4*)(p0 + ((size_t)n * 7396 + px) * 8) = v;
    }
}

// ---------------------------------------------------------------------------
// Pre-pack weights to bf16 in the exact LDS layouts.
// pw1  [5 slices][64 co][16]  : c=h*8+e -> tap=2s+h, ci=e (<3 real)
// pw234[layer][pass][tap][kl][64 co][16ci]
// ---------------------------------------------------------------------------
__global__ __launch_bounds__(256) void wpack_k(
    const float* __restrict__ w1, const float* __restrict__ w2,
    const float* __restrict__ w3, const float* __restrict__ w4,
    ushort_t* __restrict__ pw1, ushort_t* __restrict__ pw234)
{
    const int b = blockIdx.x, t = threadIdx.x;
    if (b == 0) {
        for (int idx = t; idx < 5120; idx += 256) {
            const int sl = idx >> 10, rem = idx & 1023;
            const int co = rem >> 4, c = rem & 15;
            const int h = c >> 3, e = c & 7, tap = 2 * sl + h;
            float v = 0.f;
            if (tap < 9 && e < 3) v = w1[co * 27 + e * 9 + tap];
            pw1[idx] = f2bf(v);
        }
    } else {
        const int l = (b - 1) >> 1, pass = (b - 1) & 1;
        const float* w = (l == 0) ? w2 : (l == 1) ? w3 : w4;
        ushort_t* dst = pw234 + l * 36864 + pass * 18432;
        for (int idx = t; idx < 18432; idx += 256) {
            const int tap = idx >> 11, rem = idx & 2047;
            const int kl = rem >> 10, co = (rem & 1023) >> 4, c = idx & 15;
            const int ci = pass * 32 + kl * 16 + c;
            dst[idx] = f2bf(w[co * 576 + ci * 9 + tap]);
        }
    }
}

// ---------------------------------------------------------------------------
// Zero the 1-px halo of a padded channels-last bf16 buffer [160][HP][HP][64].
// ---------------------------------------------------------------------------
template <int HP>
__global__ void border_zero_k(ushort_t* __restrict__ buf)
{
    const int n = blockIdx.x, t = threadIdx.x;
    constexpr int W = HP - 2;
    constexpr int NB = 2 * HP + 2 * W;
    for (int i = t; i < NB; i += blockDim.x) {
        int yy, xx;
        if (i < HP)            { yy = 0;            xx = i; }
        else if (i < 2 * HP)   { yy = HP - 1;       xx = i - HP; }
        else if (i < 2*HP + W) { yy = i - 2*HP + 1; xx = 0; }
        else                   { yy = i - 2*HP - W + 1; xx = HP - 1; }
        uint4* p = (uint4*)(buf + ((size_t)n * HP * HP + yy * HP + xx) * 64);
        const uint4 z = make_uint4(0u, 0u, 0u, 0u);
#pragma unroll
        for (int k = 0; k < 8; ++k) p[k] = z;
    }
}

// ---------------------------------------------------------------------------
// conv1 MFMA: 8-ch padded input, K = 5 slices of 16 (tap-pair packing).
// MT=2 M-tiles/wave, fused affine+ReLU+pool -> padded [44][44][64].
// ---------------------------------------------------------------------------
__global__ __launch_bounds__(256, 4) void conv1_mfma_k(
    const ushort_t* __restrict__ p0, const ushort_t* __restrict__ pw1,
    const float* __restrict__ gg, const float* __restrict__ bb,
    ushort_t* __restrict__ outp)
{
    constexpr int MTOT = 1128960;       // 160 * 84*84 (pre-pool, quadrant order)
    __shared__ __align__(16) ushort_t wlds[5120];

    const int tid = threadIdx.x, wv = tid >> 6, lane = tid & 63;
    const int l31 = lane & 31, h = lane >> 5;
    const int wave_m = (blockIdx.x * 4 + wv) * 64;

    for (int i = tid; i < 640; i += 256)
        ((uint4*)wlds)[i] = ((const uint4*)pw1)[i];

    long aoff[2];
#pragma unroll
    for (int t = 0; t < 2; ++t) {
        int m = wave_m + t * 32 + l31;
        if (m >= MTOT) m = 0;
        const int n = m / 7056, r = m % 7056;
        const int p = r >> 2, qd = r & 3;
        const int py = p / 42, px = p % 42;
        const int y = 2 * py + (qd >> 1), x = 2 * px + (qd & 1);
        aoff[t] = ((long)n * 7396 + y * 86 + x) * 16;
    }
    int boff[2];
#pragma unroll
    for (int nt = 0; nt < 2; ++nt) boff[nt] = (nt * 32 + l31) * 32 + h * 16;

    __syncthreads();

    f32x16 acc[2][2];
#pragma unroll
    for (int t = 0; t < 2; ++t)
#pragma unroll
        for (int nt = 0; nt < 2; ++nt)
#pragma unroll
            for (int r = 0; r < 16; ++r) acc[t][nt][r] = 0.f;

    const char* inb = (const char*)p0;
    bf16x8 aNext[2];
    {
        const int tap = h;                       // slice 0: taps 0,1
        const int toff = ((tap / 3) * 86 + tap % 3) * 16;
        aNext[0] = *(const bf16x8*)(inb + aoff[0] + toff);
        aNext[1] = *(const bf16x8*)(inb + aoff[1] + toff);
    }
#pragma unroll
    for (int s = 0; s < 5; ++s) {
        const bf16x8 a0 = aNext[0], a1 = aNext[1];
        if (s < 4) {
            int tap = 2 * (s + 1) + h;
            if (tap > 8) tap = 8;               // B is zero there; data unused
            const int toff = ((tap / 3) * 86 + tap % 3) * 16;
            aNext[0] = *(const bf16x8*)(inb + aoff[0] + toff);
            aNext[1] = *(const bf16x8*)(inb + aoff[1] + toff);
        }
#pragma unroll
        for (int nt = 0; nt < 2; ++nt) {
            const bf16x8 b =
                *(const bf16x8*)((const char*)wlds + s * 2048 + boff[nt]);
            acc[0][nt] = __builtin_amdgcn_mfma_f32_32x32x16_bf16(
                a0, b, acc[0][nt], 0, 0, 0);
            acc[1][nt] = __builtin_amdgcn_mfma_f32_32x32x16_bf16(
                a1, b, acc[1][nt], 0, 0, 0);
        }
    }

    float gv2[2], bv2[2];
#pragma unroll
    for (int nt = 0; nt < 2; ++nt) {
        gv2[nt] = gg[nt * 32 + l31];
        bv2[nt] = bb[nt * 32 + l31];
    }
#pragma unroll
    for (int t = 0; t < 2; ++t) {
#pragma unroll
        for (int g = 0; g < 4; ++g) {
            const int mbase = wave_m + t * 32 + 8 * g + 4 * h;
            if (mbase >= MTOT) continue;
            const int P = mbase >> 2;
            const int n = P / 1764, rp = P % 1764;
            const int py = rp / 42, px = rp % 42;
            ushort_t* drow =
                outp + ((size_t)n * 1936 + (py + 1) * 44 + (px + 1)) * 64;
#pragma unroll
            for (int nt = 0; nt < 2; ++nt) {
                float mx = 0.f;   // ReLU lower bound
#pragma unroll
                for (int qd = 0; qd < 4; ++qd)
                    mx = fmaxf(mx, fmaf(acc[t][nt][4 * g + qd], gv2[nt], bv2[nt]));
                drow[nt * 32 + l31] = f2bf(mx);
            }
        }
    }
}

// ---------------------------------------------------------------------------
// MFMA implicit-GEMM conv 3x3, Cin=Cout=64, bf16 in / f32 accum.
// LDS B layout [tap][kl][co][16ci] -> conflict-free b128 reads (co stride 32B).
// Register prefetch of A one tap ahead. MT = M-tiles per wave.
// EPI: 0 = affine+ReLU+2x2pool -> padded [23][23], 1 = padded write,
//      2 = compact [m][64] write.
// ---------------------------------------------------------------------------
template <int HINP, int POOL, int EPI, int MT>
__global__ __launch_bounds__(256, 4) void conv_mfma_k(
    const ushort_t* __restrict__ in, const ushort_t* __restrict__ pkw,
    const float* __restrict__ gg, const float* __restrict__ bb,
    ushort_t* __restrict__ outp)
{
    constexpr int MIMG = POOL ? 1764 : 441;
    constexpr int MTOT = 160 * MIMG;
    constexpr int CH2 = HINP * HINP * 64;

    __shared__ __align__(16) ushort_t wlds[18432];

    const int tid = threadIdx.x, wv = tid >> 6, lane = tid & 63;
    const int l31 = lane & 31, h = lane >> 5;
    const int wave_m = (blockIdx.x * 4 + wv) * (MT * 32);

    long aoff[MT];
#pragma unroll
    for (int t = 0; t < MT; ++t) {
        int m = wave_m + t * 32 + l31;
        if (m >= MTOT) m = 0;
        const int n = m / MIMG, r = m % MIMG;
        int y, x;
        if (POOL) {
            const int p = r >> 2, qd = r & 3;
            const int py = p / 21, px = p % 21;
            y = 2 * py + (qd >> 1); x = 2 * px + (qd & 1);
        } else {
            y = r / 21; x = r % 21;
        }
        aoff[t] = ((long)n * CH2 + (y * HINP + x) * 64) * 2 + h * 16;
    }
    int boff[2];
#pragma unroll
    for (int nt = 0; nt < 2; ++nt) boff[nt] = (nt * 32 + l31) * 32 + h * 16;

    f32x16 acc[MT][2];
#pragma unroll
    for (int t = 0; t < MT; ++t)
#pragma unroll
        for (int nt = 0; nt < 2; ++nt)
#pragma unroll
            for (int r = 0; r < 16; ++r) acc[t][nt][r] = 0.f;

    const char* inb = (const char*)in;

    for (int pass = 0; pass < 2; ++pass) {
        if (pass) __syncthreads();
        const uint4* wsrc = (const uint4*)(pkw + pass * 18432);
        for (int i = tid; i < 2304; i += 256) ((uint4*)wlds)[i] = wsrc[i];
        __syncthreads();

        bf16x8 aNext[MT][2];
#pragma unroll
        for (int t = 0; t < MT; ++t)
#pragma unroll
            for (int kl = 0; kl < 2; ++kl)
                aNext[t][kl] = *(const bf16x8*)(
                    inb + aoff[t] + (pass * 2 + kl) * 32);

#pragma unroll
        for (int tap = 0; tap < 9; ++tap) {
            bf16x8 aCur[MT][2];
#pragma unroll
            for (int t = 0; t < MT; ++t)
#pragma unroll
                for (int kl = 0; kl < 2; ++kl) aCur[t][kl] = aNext[t][kl];
            if (tap < 8) {
                const int toff = (((tap + 1) / 3) * HINP + (tap + 1) % 3) * 128;
#pragma unroll
                for (int t = 0; t < MT; ++t)
#pragma unroll
                    for (int kl = 0; kl < 2; ++kl)
                        aNext[t][kl] = *(const bf16x8*)(
                            inb + aoff[t] + toff + (pass * 2 + kl) * 32);
            }
#pragma unroll
            for (int kl = 0; kl < 2; ++kl) {
#pragma unroll
                for (int nt = 0; nt < 2; ++nt) {
                    const bf16x8 b = *(const bf16x8*)(
                        (const char*)wlds + (tap * 2 + kl) * 2048 + boff[nt]);
#pragma unroll
                    for (int t = 0; t < MT; ++t)
                        acc[t][nt] = __builtin_amdgcn_mfma_f32_32x32x16_bf16(
                            aCur[t][kl], b, acc[t][nt], 0, 0, 0);
                }
            }
        }
    }

    float gv2[2], bv2[2];
#pragma unroll
    for (int nt = 0; nt < 2; ++nt) {
        gv2[nt] = gg[nt * 32 + l31];
        bv2[nt] = bb[nt * 32 + l31];
    }

    if (EPI == 0) {
#pragma unroll
        for (int t = 0; t < MT; ++t) {
#pragma unroll
            for (int g = 0; g < 4; ++g) {
                const int mbase = wave_m + t * 32 + 8 * g + 4 * h;
                if (mbase >= MTOT) continue;
                const int P = mbase >> 2;
                const int n = P / 441, rp = P % 441;
                const int py = rp / 21, px = rp % 21;
                ushort_t* drow =
                    outp + ((size_t)n * 529 + (py + 1) * 23 + (px + 1)) * 64;
#pragma unroll
                for (int nt = 0; nt < 2; ++nt) {
                    float mx = 0.f;
#pragma unroll
                    for (int qd = 0; qd < 4; ++qd)
                        mx = fmaxf(mx,
                                   fmaf(acc[t][nt][4 * g + qd], gv2[nt], bv2[nt]));
                    drow[nt * 32 + l31] = f2bf(mx);
                }
            }
        }
    } else {
#pragma unroll
        for (int t = 0; t < MT; ++t) {
#pragma unroll
            for (int r = 0; r < 16; ++r) {
                const int m = wave_m + t * 32 + (r & 3) + 8 * (r >> 2) + 4 * h;
                if (m >= MTOT) continue;
                size_t obase;
                if (EPI == 1) {
                    const int n = m / 441, rr = m % 441;
                    const int y = rr / 21, x = rr % 21;
                    obase = ((size_t)n * 529 + (y + 1) * 23 + (x + 1)) * 64;
                } else {
                    obase = (size_t)m * 64;
                }
#pragma unroll
                for (int nt = 0; nt < 2; ++nt) {
                    const float v =
                        fmaxf(fmaf(acc[t][nt][r], gv2[nt], bv2[nt]), 0.f);
                    outp[obase + nt * 32 + l31] = f2bf(v);
                }
            }
        }
    }
}

// ---------------------------------------------------------------------------
// Global average pool over compact channels-last conv4 output -> emb f32.
// ---------------------------------------------------------------------------
__global__ __launch_bounds__(256) void gap2_k(const ushort_t* __restrict__ o4,
                                              float* __restrict__ emb)
{
    const int n = blockIdx.x, t = threadIdx.x;
    const int co = t & 63, part = t >> 6;
    float s = 0.f;
    for (int pix = part; pix < 441; pix += 4)
        s += bf2f(o4[((size_t)n * 441 + pix) * 64 + co]);
    __shared__ float red[4][64];
    red[part][co] = s;
    __syncthreads();
    if (part == 0)
        emb[(size_t)n * 64 + co] =
            (red[0][co] + red[1][co] + red[2][co] + red[3][co]) * (1.f / 441.f);
}

// ---------------------------------------------------------------------------
// Relation head (unchanged).
// ---------------------------------------------------------------------------
__global__ __launch_bounds__(64) void relation_k(
    const float* __restrict__ emb,
    const float* __restrict__ fc1w, const float* __restrict__ fc1b,
    const float* __restrict__ fc2w, const float* __restrict__ fc2b,
    const float* __restrict__ fc3w, const float* __restrict__ fc3b,
    float* __restrict__ out)
{
    const int idx = blockIdx.x;
    const int w = idx % 5;
    const int bq = idx / 5;
    const int b = bq / 15;
    const int t = threadIdx.x;

    __shared__ float dif[64], h1v[64], h2v[32];
    const float qv = emb[(size_t)bq * 64 + t];

    float ssum = 0.f;
    for (int s = 0; s < 5; ++s) {
        const int simg = 60 + ((b * 5 + w) * 5 + s);
        __syncthreads();
        dif[t] = fabsf(qv - emb[(size_t)simg * 64 + t]);
        __syncthreads();
        float a = fc1b[t];
        for (int d = 0; d < 64; ++d) a = fmaf(fc1w[t * 64 + d], dif[d], a);
        a = fmaxf(a, 0.f);
        __syncthreads();
        h1v[t] = a;
        __syncthreads();
        if (t < 32) {
            float h = fc2b[t];
            for (int d = 0; d < 64; ++d) h = fmaf(fc2w[t * 64 + d], h1v[d], h);
            h2v[t] = fmaxf(h, 0.f);
        }
        __syncthreads();
        float p = (t < 32) ? fc3w[t] * h2v[t] : 0.f;
#pragma unroll
        for (int off = 32; off > 0; off >>= 1) p += __shfl_down(p, off);
        if (t == 0) {
            const float z = p + fc3b[0];
            ssum += 1.f / (1.f + expf(-z));
        }
    }
    if (t == 0) out[idx] = ssum * 0.2f;
}

// ---------------------------------------------------------------------------
extern "C" void kernel_launch(void* const* d_in, const int* in_sizes, int n_in,
                              void* d_out, int out_size, void* d_ws, size_t ws_size,
                              hipStream_t stream)
{
    const float* q    = (const float*)d_in[0];
    const float* s    = (const float*)d_in[1];
    const float* w1   = (const float*)d_in[2];
    const float* g1   = (const float*)d_in[3];
    const float* b1p  = (const float*)d_in[4];
    const float* w2   = (const float*)d_in[5];
    const float* g2   = (const float*)d_in[6];
    const float* b2p  = (const float*)d_in[7];
    const float* w3   = (const float*)d_in[8];
    const float* g3   = (const float*)d_in[9];
    const float* b3p  = (const float*)d_in[10];
    const float* w4   = (const float*)d_in[11];
    const float* g4   = (const float*)d_in[12];
    const float* b4p  = (const float*)d_in[13];
    const float* fc1w = (const float*)d_in[14];
    const float* fc1b = (const float*)d_in[15];
    const float* fc2w = (const float*)d_in[16];
    const float* fc2b = (const float*)d_in[17];
    const float* fc3w = (const float*)d_in[18];
    const float* fc3b = (const float*)d_in[19];
    float* out = (float*)d_out;

    char* ws = (char*)d_ws;
    // region A [0, 19,865,600): P0 packed input (18.93MB); after conv1 done,
    //   P3 @ +0 (10,833,920) and O4 @ +10,833,920 (9,031,680; tail spills
    //   into P1's head, which is dead by conv4).
    ushort_t* P0   = (ushort_t*)ws;
    ushort_t* P3   = (ushort_t*)ws;
    ushort_t* O4   = (ushort_t*)(ws + 10833920);
    ushort_t* P1   = (ushort_t*)(ws + 19865600);   // [160][44][44][64] 39,649,280
    ushort_t* P2   = (ushort_t*)(ws + 59514880);   // [160][23][23][64] 10,833,920
    float*    embv = (float*)   (ws + 70348800);   // 160*64 f32 = 40,960
    ushort_t* pw1  = (ushort_t*)(ws + 70389760);   // 5120 ushorts
    ushort_t* pw234= (ushort_t*)(ws + 70400000);   // 3 * 36864 ushorts

    wpack_k<<<dim3(7), 256, 0, stream>>>(w1, w2, w3, w4, pw1, pw234);
    pack_k<<<dim3(160), 256, 0, stream>>>(q, s, P0);
    border_zero_k<44><<<dim3(160), 192, 0, stream>>>(P1);
    border_zero_k<23><<<dim3(160), 96, 0, stream>>>(P2);

    // conv1: MFMA over packed 8-ch input, pool -> P1.  M=1,128,960 -> 4410 blocks
    conv1_mfma_k<<<dim3(4410), 256, 0, stream>>>(P0, pw1, g1, b1p, P1);
    // P3 aliases P0 -> zero its halo only after conv1 consumed P0
    border_zero_k<23><<<dim3(160), 96, 0, stream>>>(P3);

    // conv2: MT=2, pool -> P2.  M=282,240 -> 1103 blocks
    conv_mfma_k<44, 1, 0, 2><<<dim3(1103), 256, 0, stream>>>(
        P1, pw234, g2, b2p, P2);
    // conv3: MT=1 -> P3.  M=70,560 -> 552 blocks
    conv_mfma_k<23, 0, 1, 1><<<dim3(552), 256, 0, stream>>>(
        P2, pw234 + 36864, g3, b3p, P3);
    // conv4: MT=1 -> compact O4
    conv_mfma_k<23, 0, 2, 1><<<dim3(552), 256, 0, stream>>>(
        P3, pw234 + 2 * 36864, g4, b4p, O4);

    gap2_k<<<dim3(160), 256, 0, stream>>>(O4, embv);
    relation_k<<<dim3(300), 64, 0, stream>>>(
        embv, fc1w, fc1b, fc2w, fc2b, fc3w, fc3b, out);
}

// Round 5
// 197.416 us; speedup vs baseline: 4.9930x; 1.0128x over previous
//
#include <hip/hip_runtime.h>
#include <math.h>

typedef unsigned short ushort_t;
typedef __attribute__((ext_vector_type(8))) short bf16x8;
typedef __attribute__((ext_vector_type(16))) float f32x16;

__device__ __forceinline__ ushort_t f2bf(float f) {
    unsigned u = __float_as_uint(f);
    u += 0x7fffu + ((u >> 16) & 1u);          // RNE
    return (ushort_t)(u >> 16);
}
__device__ __forceinline__ float bf2f(ushort_t h) {
    return __uint_as_float(((unsigned)h) << 16);
}

// ---------------------------------------------------------------------------
// Pack NCHW f32 input (3ch) -> padded channels-last bf16 [160][86][86][8]
// ---------------------------------------------------------------------------
__global__ __launch_bounds__(256) void pack_k(const float* __restrict__ q,
                                              const float* __restrict__ s,
                                              ushort_t* __restrict__ p0)
{
    const int n = blockIdx.x;
    const float* src; int nn;
    if (n < 60) { src = q; nn = n; } else { src = s; nn = n - 60; }
    const float* img = src + (size_t)nn * 3 * 7056;
    for (int px = threadIdx.x; px < 7396; px += 256) {
        const int y = px / 86, x = px % 86;
        uint4 v = make_uint4(0u, 0u, 0u, 0u);
        if (y >= 1 && y <= 84 && x >= 1 && x <= 84) {
            const int o = (y - 1) * 84 + (x - 1);
            const unsigned c0 = f2bf(img[o]);
            const unsigned c1 = f2bf(img[7056 + o]);
            const unsigned c2 = f2bf(img[14112 + o]);
            v.x = c0 | (c1 << 16);
            v.y = c2;
        }
        *(uint4*)(p0 + ((size_t)n * 7396 + px) * 8) = v;
    }
}

// ---------------------------------------------------------------------------
// Pre-pack weights to bf16 in the exact LDS layouts.
// pw1  [5 slices][64 co][16c]         : c=h*8+e -> tap=2s+h, ci=e (<3 real)
// pw234[layer][pass][tap][kl][h][co][8c] : ci = pass*32 + kl*16 + h*8 + c
//   (lane-linear within each (tap,kl): lane reads byte h*1024+co*16 ->
//    8-lane beats are 128 contiguous bytes -> conflict-free b128)
// ---------------------------------------------------------------------------
__global__ __launch_bounds__(256) void wpack_k(
    const float* __restrict__ w1, const float* __restrict__ w2,
    const float* __restrict__ w3, const float* __restrict__ w4,
    ushort_t* __restrict__ pw1, ushort_t* __restrict__ pw234)
{
    const int b = blockIdx.x, t = threadIdx.x;
    if (b == 0) {
        for (int idx = t; idx < 5120; idx += 256) {
            const int sl = idx >> 10, rem = idx & 1023;
            const int co = rem >> 4, c = rem & 15;
            const int h = c >> 3, e = c & 7, tap = 2 * sl + h;
            float v = 0.f;
            if (tap < 9 && e < 3) v = w1[co * 27 + e * 9 + tap];
            pw1[idx] = f2bf(v);
        }
    } else {
        const int l = (b - 1) >> 1, pass = (b - 1) & 1;
        const float* w = (l == 0) ? w2 : (l == 1) ? w3 : w4;
        ushort_t* dst = pw234 + l * 36864 + pass * 18432;
        for (int idx = t; idx < 18432; idx += 256) {
            const int c  = idx & 7;
            const int co = (idx >> 3) & 63;
            const int h  = (idx >> 9) & 1;
            const int kl = (idx >> 10) & 1;
            const int tap = idx >> 11;
            const int ci = pass * 32 + kl * 16 + h * 8 + c;
            dst[idx] = f2bf(w[co * 576 + ci * 9 + tap]);
        }
    }
}

// ---------------------------------------------------------------------------
// Zero the 1-px halo of a padded channels-last bf16 buffer [160][HP][HP][64].
// ---------------------------------------------------------------------------
template <int HP>
__global__ void border_zero_k(ushort_t* __restrict__ buf)
{
    const int n = blockIdx.x, t = threadIdx.x;
    constexpr int W = HP - 2;
    constexpr int NB = 2 * HP + 2 * W;
    for (int i = t; i < NB; i += blockDim.x) {
        int yy, xx;
        if (i < HP)            { yy = 0;            xx = i; }
        else if (i < 2 * HP)   { yy = HP - 1;       xx = i - HP; }
        else if (i < 2*HP + W) { yy = i - 2*HP + 1; xx = 0; }
        else                   { yy = i - 2*HP - W + 1; xx = HP - 1; }
        uint4* p = (uint4*)(buf + ((size_t)n * HP * HP + yy * HP + xx) * 64);
        const uint4 z = make_uint4(0u, 0u, 0u, 0u);
#pragma unroll
        for (int k = 0; k < 8; ++k) p[k] = z;
    }
}

// ---------------------------------------------------------------------------
// conv1 MFMA: 8-ch padded input, K = 5 slices of 16 (tap-pair packing).
// MT=2, ring-2 A prefetch, fused affine+ReLU+pool -> padded [44][44][64].
// ---------------------------------------------------------------------------
__global__ __launch_bounds__(256, 4) void conv1_mfma_k(
    const ushort_t* __restrict__ p0, const ushort_t* __restrict__ pw1,
    const float* __restrict__ gg, const float* __restrict__ bb,
    ushort_t* __restrict__ outp)
{
    constexpr int MTOT = 1128960;       // 160 * 84*84 (pre-pool, quadrant order)
    __shared__ __align__(16) ushort_t wlds[5120];

    const int tid = threadIdx.x, wv = tid >> 6, lane = tid & 63;
    const int l31 = lane & 31, h = lane >> 5;
    const int wave_m = (blockIdx.x * 4 + wv) * 64;

    for (int i = tid; i < 640; i += 256)
        ((uint4*)wlds)[i] = ((const uint4*)pw1)[i];

    long aoff[2];
#pragma unroll
    for (int t = 0; t < 2; ++t) {
        int m = wave_m + t * 32 + l31;
        if (m >= MTOT) m = 0;
        const int n = m / 7056, r = m % 7056;
        const int p = r >> 2, qd = r & 3;
        const int py = p / 42, px = p % 42;
        const int y = 2 * py + (qd >> 1), x = 2 * px + (qd & 1);
        aoff[t] = ((long)n * 7396 + y * 86 + x) * 16;
    }
    int boff[2];
#pragma unroll
    for (int nt = 0; nt < 2; ++nt) boff[nt] = (nt * 32 + l31) * 32 + h * 16;

    __syncthreads();

    f32x16 acc[2][2];
#pragma unroll
    for (int t = 0; t < 2; ++t)
#pragma unroll
        for (int nt = 0; nt < 2; ++nt)
#pragma unroll
            for (int r = 0; r < 16; ++r) acc[t][nt][r] = 0.f;

    const char* inb = (const char*)p0;
    bf16x8 abuf[2][2];   // [slot][Mtile]

#define C1_LD(S, SLOT)                                                     \
    {                                                                      \
        int tap_ = 2 * (S) + h;                                            \
        if (tap_ > 8) tap_ = 8;   /* B is zero there; data unused */       \
        const int toff_ = ((tap_ / 3) * 86 + tap_ % 3) * 16;               \
        abuf[SLOT][0] = *(const bf16x8*)(inb + aoff[0] + toff_);           \
        abuf[SLOT][1] = *(const bf16x8*)(inb + aoff[1] + toff_);           \
    }

    C1_LD(0, 0)
    C1_LD(1, 1)
#pragma unroll
    for (int s = 0; s < 5; ++s) {
        const int slot = s & 1;
#pragma unroll
        for (int nt = 0; nt < 2; ++nt) {
            const bf16x8 b =
                *(const bf16x8*)((const char*)wlds + s * 2048 + boff[nt]);
            acc[0][nt] = __builtin_amdgcn_mfma_f32_32x32x16_bf16(
                abuf[slot][0], b, acc[0][nt], 0, 0, 0);
            acc[1][nt] = __builtin_amdgcn_mfma_f32_32x32x16_bf16(
                abuf[slot][1], b, acc[1][nt], 0, 0, 0);
        }
        if (s < 3) C1_LD(s + 2, slot)
    }
#undef C1_LD

    float gv2[2], bv2[2];
#pragma unroll
    for (int nt = 0; nt < 2; ++nt) {
        gv2[nt] = gg[nt * 32 + l31];
        bv2[nt] = bb[nt * 32 + l31];
    }
#pragma unroll
    for (int t = 0; t < 2; ++t) {
#pragma unroll
        for (int g = 0; g < 4; ++g) {
            const int mbase = wave_m + t * 32 + 8 * g + 4 * h;
            if (mbase >= MTOT) continue;
            const int P = mbase >> 2;
            const int n = P / 1764, rp = P % 1764;
            const int py = rp / 42, px = rp % 42;
            ushort_t* drow =
                outp + ((size_t)n * 1936 + (py + 1) * 44 + (px + 1)) * 64;
#pragma unroll
            for (int nt = 0; nt < 2; ++nt) {
                float mx = 0.f;   // ReLU lower bound
#pragma unroll
                for (int qd = 0; qd < 4; ++qd)
                    mx = fmaxf(mx, fmaf(acc[t][nt][4 * g + qd], gv2[nt], bv2[nt]));
                drow[nt * 32 + l31] = f2bf(mx);
            }
        }
    }
}

// ---------------------------------------------------------------------------
// MFMA implicit-GEMM conv 3x3, Cin=Cout=64, bf16 in / f32 accum.
// B LDS layout [tap][kl][h][co][8ci] -> lane-linear, conflict-free b128.
// Ring-3 A register prefetch, carried across the pass boundary.
// EPI: 0 = affine+ReLU+2x2pool -> padded [23][23], 1 = padded write,
//      2 = compact [m][64] write.  WPE: min waves/EU for launch_bounds.
// ---------------------------------------------------------------------------
template <int HINP, int POOL, int EPI, int MT, int WPE>
__global__ __launch_bounds__(256, WPE) void conv_mfma_k(
    const ushort_t* __restrict__ in, const ushort_t* __restrict__ pkw,
    const float* __restrict__ gg, const float* __restrict__ bb,
    ushort_t* __restrict__ outp)
{
    constexpr int MIMG = POOL ? 1764 : 441;
    constexpr int MTOT = 160 * MIMG;
    constexpr int CH2 = HINP * HINP * 64;

    __shared__ __align__(16) ushort_t wlds[18432];

    const int tid = threadIdx.x, wv = tid >> 6, lane = tid & 63;
    const int l31 = lane & 31, h = lane >> 5;
    const int wave_m = (blockIdx.x * 4 + wv) * (MT * 32);

    long aoff[MT];
#pragma unroll
    for (int t = 0; t < MT; ++t) {
        int m = wave_m + t * 32 + l31;
        if (m >= MTOT) m = 0;
        const int n = m / MIMG, r = m % MIMG;
        int y, x;
        if (POOL) {
            const int p = r >> 2, qd = r & 3;
            const int py = p / 21, px = p % 21;
            y = 2 * py + (qd >> 1); x = 2 * px + (qd & 1);
        } else {
            y = r / 21; x = r % 21;
        }
        aoff[t] = ((long)n * CH2 + (y * HINP + x) * 64) * 2 + h * 16;
    }
    // lane-linear B offset: byte = (tap*2+kl)*2048 + h*1024 + co*16
    int boff[2];
#pragma unroll
    for (int nt = 0; nt < 2; ++nt) boff[nt] = h * 1024 + (nt * 32 + l31) * 16;

    f32x16 acc[MT][2];
#pragma unroll
    for (int t = 0; t < MT; ++t)
#pragma unroll
        for (int nt = 0; nt < 2; ++nt)
#pragma unroll
            for (int r = 0; r < 16; ++r) acc[t][nt][r] = 0.f;

    const char* inb = (const char*)in;
    bf16x8 abuf[3][MT][2];   // [slot][Mtile][kl]

#define LD_A(PS, TAP, SLOT)                                                \
    {                                                                      \
        const int toff_ = (((TAP) / 3) * HINP + (TAP) % 3) * 128;          \
        _Pragma("unroll")                                                  \
        for (int t = 0; t < MT; ++t) {                                     \
            _Pragma("unroll")                                              \
            for (int kl = 0; kl < 2; ++kl)                                 \
                abuf[SLOT][t][kl] = *(const bf16x8*)(                      \
                    inb + aoff[t] + toff_ + ((PS) * 2 + kl) * 32);         \
        }                                                                  \
    }

#define MFMA_STEP(TAP, SLOT)                                               \
    {                                                                      \
        _Pragma("unroll")                                                  \
        for (int kl = 0; kl < 2; ++kl) {                                   \
            _Pragma("unroll")                                              \
            for (int nt = 0; nt < 2; ++nt) {                               \
                const bf16x8 b = *(const bf16x8*)(                         \
                    (const char*)wlds + ((TAP) * 2 + kl) * 2048 + boff[nt]); \
                _Pragma("unroll")                                          \
                for (int t = 0; t < MT; ++t)                               \
                    acc[t][nt] = __builtin_amdgcn_mfma_f32_32x32x16_bf16(  \
                        abuf[SLOT][t][kl], b, acc[t][nt], 0, 0, 0);        \
            }                                                              \
        }                                                                  \
    }

    // ---- pass 0 ----
    {
        const uint4* wsrc = (const uint4*)pkw;
        for (int i = tid; i < 2304; i += 256) ((uint4*)wlds)[i] = wsrc[i];
    }
    __syncthreads();
    LD_A(0, 0, 0)
    LD_A(0, 1, 1)
    LD_A(0, 2, 2)
#pragma unroll
    for (int tap = 0; tap < 9; ++tap) {
        const int slot = tap % 3;
        MFMA_STEP(tap, slot)
        if (tap < 6) { LD_A(0, tap + 3, slot) }
        else         { LD_A(1, tap - 6, slot) }   // pass-1 prologue in flight
    }
    // ---- pass 1 ----
    __syncthreads();
    {
        const uint4* wsrc = (const uint4*)(pkw + 18432);
        for (int i = tid; i < 2304; i += 256) ((uint4*)wlds)[i] = wsrc[i];
    }
    __syncthreads();
#pragma unroll
    for (int tap = 0; tap < 9; ++tap) {
        const int slot = tap % 3;
        MFMA_STEP(tap, slot)
        if (tap < 6) LD_A(1, tap + 3, slot)
    }
#undef LD_A
#undef MFMA_STEP

    float gv2[2], bv2[2];
#pragma unroll
    for (int nt = 0; nt < 2; ++nt) {
        gv2[nt] = gg[nt * 32 + l31];
        bv2[nt] = bb[nt * 32 + l31];
    }

    if (EPI == 0) {
#pragma unroll
        for (int t = 0; t < MT; ++t) {
#pragma unroll
            for (int g = 0; g < 4; ++g) {
                const int mbase = wave_m + t * 32 + 8 * g + 4 * h;
                if (mbase >= MTOT) continue;
                const int P = mbase >> 2;
                const int n = P / 441, rp = P % 441;
                const int py = rp / 21, px = rp % 21;
                ushort_t* drow =
                    outp + ((size_t)n * 529 + (py + 1) * 23 + (px + 1)) * 64;
#pragma unroll
                for (int nt = 0; nt < 2; ++nt) {
                    float mx = 0.f;
#pragma unroll
                    for (int qd = 0; qd < 4; ++qd)
                        mx = fmaxf(mx,
                                   fmaf(acc[t][nt][4 * g + qd], gv2[nt], bv2[nt]));
                    drow[nt * 32 + l31] = f2bf(mx);
                }
            }
        }
    } else {
#pragma unroll
        for (int t = 0; t < MT; ++t) {
#pragma unroll
            for (int r = 0; r < 16; ++r) {
                const int m = wave_m + t * 32 + (r & 3) + 8 * (r >> 2) + 4 * h;
                if (m >= MTOT) continue;
                size_t obase;
                if (EPI == 1) {
                    const int n = m / 441, rr = m % 441;
                    const int y = rr / 21, x = rr % 21;
                    obase = ((size_t)n * 529 + (y + 1) * 23 + (x + 1)) * 64;
                } else {
                    obase = (size_t)m * 64;
                }
#pragma unroll
                for (int nt = 0; nt < 2; ++nt) {
                    const float v =
                        fmaxf(fmaf(acc[t][nt][r], gv2[nt], bv2[nt]), 0.f);
                    outp[obase + nt * 32 + l31] = f2bf(v);
                }
            }
        }
    }
}

// ---------------------------------------------------------------------------
// Global average pool over compact channels-last conv4 output -> emb f32.
// ---------------------------------------------------------------------------
__global__ __launch_bounds__(256) void gap2_k(const ushort_t* __restrict__ o4,
                                              float* __restrict__ emb)
{
    const int n = blockIdx.x, t = threadIdx.x;
    const int co = t & 63, part = t >> 6;
    float s = 0.f;
    for (int pix = part; pix < 441; pix += 4)
        s += bf2f(o4[((size_t)n * 441 + pix) * 64 + co]);
    __shared__ float red[4][64];
    red[part][co] = s;
    __syncthreads();
    if (part == 0)
        emb[(size_t)n * 64 + co] =
            (red[0][co] + red[1][co] + red[2][co] + red[3][co]) * (1.f / 441.f);
}

// ---------------------------------------------------------------------------
// Relation head (unchanged).
// ---------------------------------------------------------------------------
__global__ __launch_bounds__(64) void relation_k(
    const float* __restrict__ emb,
    const float* __restrict__ fc1w, const float* __restrict__ fc1b,
    const float* __restrict__ fc2w, const float* __restrict__ fc2b,
    const float* __restrict__ fc3w, const float* __restrict__ fc3b,
    float* __restrict__ out)
{
    const int idx = blockIdx.x;
    const int w = idx % 5;
    const int bq = idx / 5;
    const int b = bq / 15;
    const int t = threadIdx.x;

    __shared__ float dif[64], h1v[64], h2v[32];
    const float qv = emb[(size_t)bq * 64 + t];

    float ssum = 0.f;
    for (int s = 0; s < 5; ++s) {
        const int simg = 60 + ((b * 5 + w) * 5 + s);
        __syncthreads();
        dif[t] = fabsf(qv - emb[(size_t)simg * 64 + t]);
        __syncthreads();
        float a = fc1b[t];
        for (int d = 0; d < 64; ++d) a = fmaf(fc1w[t * 64 + d], dif[d], a);
        a = fmaxf(a, 0.f);
        __syncthreads();
        h1v[t] = a;
        __syncthreads();
        if (t < 32) {
            float h = fc2b[t];
            for (int d = 0; d < 64; ++d) h = fmaf(fc2w[t * 64 + d], h1v[d], h);
            h2v[t] = fmaxf(h, 0.f);
        }
        __syncthreads();
        float p = (t < 32) ? fc3w[t] * h2v[t] : 0.f;
#pragma unroll
        for (int off = 32; off > 0; off >>= 1) p += __shfl_down(p, off);
        if (t == 0) {
            const float z = p + fc3b[0];
            ssum += 1.f / (1.f + expf(-z));
        }
    }
    if (t == 0) out[idx] = ssum * 0.2f;
}

// ---------------------------------------------------------------------------
extern "C" void kernel_launch(void* const* d_in, const int* in_sizes, int n_in,
                              void* d_out, int out_size, void* d_ws, size_t ws_size,
                              hipStream_t stream)
{
    const float* q    = (const float*)d_in[0];
    const float* s    = (const float*)d_in[1];
    const float* w1   = (const float*)d_in[2];
    const float* g1   = (const float*)d_in[3];
    const float* b1p  = (const float*)d_in[4];
    const float* w2   = (const float*)d_in[5];
    const float* g2   = (const float*)d_in[6];
    const float* b2p  = (const float*)d_in[7];
    const float* w3   = (const float*)d_in[8];
    const float* g3   = (const float*)d_in[9];
    const float* b3p  = (const float*)d_in[10];
    const float* w4   = (const float*)d_in[11];
    const float* g4   = (const float*)d_in[12];
    const float* b4p  = (const float*)d_in[13];
    const float* fc1w = (const float*)d_in[14];
    const float* fc1b = (const float*)d_in[15];
    const float* fc2w = (const float*)d_in[16];
    const float* fc2b = (const float*)d_in[17];
    const float* fc3w = (const float*)d_in[18];
    const float* fc3b = (const float*)d_in[19];
    float* out = (float*)d_out;

    char* ws = (char*)d_ws;
    // region A [0, 19,865,600): P0 packed input (18.93MB); after conv1 done,
    //   P3 @ +0 and O4 @ +10,833,920 (tail spills into P1's head, dead then).
    ushort_t* P0   = (ushort_t*)ws;
    ushort_t* P3   = (ushort_t*)ws;
    ushort_t* O4   = (ushort_t*)(ws + 10833920);
    ushort_t* P1   = (ushort_t*)(ws + 19865600);   // [160][44][44][64] 39,649,280
    ushort_t* P2   = (ushort_t*)(ws + 59514880);   // [160][23][23][64] 10,833,920
    float*    embv = (float*)   (ws + 70348800);   // 160*64 f32 = 40,960
    ushort_t* pw1  = (ushort_t*)(ws + 70389760);   // 5120 ushorts
    ushort_t* pw234= (ushort_t*)(ws + 70400000);   // 3 * 36864 ushorts

    wpack_k<<<dim3(7), 256, 0, stream>>>(w1, w2, w3, w4, pw1, pw234);
    pack_k<<<dim3(160), 256, 0, stream>>>(q, s, P0);
    border_zero_k<44><<<dim3(160), 192, 0, stream>>>(P1);
    border_zero_k<23><<<dim3(160), 96, 0, stream>>>(P2);

    // conv1: MFMA over packed 8-ch input, pool -> P1.  M=1,128,960 -> 4410 blocks
    conv1_mfma_k<<<dim3(4410), 256, 0, stream>>>(P0, pw1, g1, b1p, P1);
    // P3 aliases P0 -> zero its halo only after conv1 consumed P0
    border_zero_k<23><<<dim3(160), 96, 0, stream>>>(P3);

    // conv2: MT=2, deep-ILP (2 waves/EU min), pool -> P2.  1103 blocks
    conv_mfma_k<44, 1, 0, 2, 2><<<dim3(1103), 256, 0, stream>>>(
        P1, pw234, g2, b2p, P2);
    // conv3: MT=1, 4 blocks/CU -> P3.  552 blocks
    conv_mfma_k<23, 0, 1, 1, 4><<<dim3(552), 256, 0, stream>>>(
        P2, pw234 + 36864, g3, b3p, P3);
    // conv4: MT=1 -> compact O4
    conv_mfma_k<23, 0, 2, 1, 4><<<dim3(552), 256, 0, stream>>>(
        P3, pw234 + 2 * 36864, g4, b4p, O4);

    gap2_k<<<dim3(160), 256, 0, stream>>>(O4, embv);
    relation_k<<<dim3(300), 64, 0, stream>>>(
        embv, fc1w, fc1b, fc2w, fc2b, fc3w, fc3b, out);
}